// Round 12
// baseline (47.073 us; speedup 1.0000x reference)
//
#include <hip/hip_runtime.h>
#include <stdint.h>

typedef _Float16 f16x8 __attribute__((ext_vector_type(8)));
typedef float    f32x4 __attribute__((ext_vector_type(4)));
typedef float    f32x2 __attribute__((ext_vector_type(2)));

union FragU { unsigned u[4]; f16x8 h; };

__device__ __forceinline__ unsigned pkh(float a, float b) {
    return __builtin_bit_cast(unsigned, __builtin_amdgcn_cvt_pkrtz(a, b));
}
__device__ __forceinline__ unsigned short h16(float a) {
    return __builtin_bit_cast(unsigned short, (_Float16)a);
}

#define MFMA(A, B, C) __builtin_amdgcn_mfma_f32_16x16x32_f16((A).h, (B).h, (C), 0, 0, 0)

#define K1 (-1.5339807878856412e-03f)   /* -2*pi/4096 */
#define K2 (-2.4543692606170259e-02f)   /* -2*pi/256  */

// 4096-pt FFT = 3 radix-16 stages as complex 16x16 GEMMs (K=32 stacking).
// One block per (b,h) row, 4 waves. NO output-transpose buffer: stage 3 is
// computed per-m2-tile with A=M (rows=n3), B=U[o3][m1] (cols=m1), so
// D[n3=4g+reg][m1=c] stores are lane-contiguous float2 (4x128B dense
// segments per instruction). 2 barriers total.
// LDS 32 KiB: LDS1 [m1][o3][o2] @0/@8192 ; LDS2 [m2][m1][o3] @16384/@24576
// with o3-slot swizzle slot^(m1&3)^(m1>>2) -> b64 reads conflict-free.
__global__ __launch_bounds__(256, 6) void fft4096_mfma(
    const float* __restrict__ xre, const float* __restrict__ xim,
    const float* __restrict__ mat16, float* __restrict__ out, int H)
{
    __shared__ __align__(16) unsigned char smem[32768];

    const int t = threadIdx.x;
    const int w = t >> 6;          // wave 0..3
    const int l = t & 63;
    const int g = l >> 4;          // lane group 0..3
    const int c = l & 15;          // lane col 0..15
    const int bh = blockIdx.x;
    const int h  = bh % H;
    const size_t base = (size_t)bh * 4096;

    // ---- all 64 stage-1 input loads issued first (deep MLP) ----
    float xr[4][4], xi[4][4];
#pragma unroll
    for (int p = 0; p < 4; ++p) {
        const int col = (4 * w + p) * 16 + c;
#pragma unroll
        for (int jj = 0; jj < 4; ++jj) {
            xr[p][jj] = xre[base + (size_t)((4 * g + jj) * 256 + col)];
            xi[p][jj] = xim[base + (size_t)((4 * g + jj) * 256 + col)];
        }
    }

    // ---- M fragment (A = [Mr | Mi], reused by ALL THREE stages) ----
    const float* Mb = mat16 + (size_t)h * 512 + (size_t)c * 32 + g * 8;
    const float4 mf0 = *(const float4*)Mb;
    const float4 mf1 = *(const float4*)(Mb + 4);
    FragU Afrag;
    Afrag.u[0] = pkh(mf0.x, mf0.z); Afrag.u[1] = pkh(mf1.x, mf1.z);
    Afrag.u[2] = pkh(mf0.y, mf0.w); Afrag.u[3] = pkh(mf1.y, mf1.w);

    const f32x4 zero = {0.f, 0.f, 0.f, 0.f};

    // ================= stage 1: Y1[m1][j] = sum_o M[m1][o] x[o*256+j] =========
    f32x4 s1r[4], s1i[4];
#pragma unroll
    for (int p = 0; p < 4; ++p) {
        const unsigned rp0 = pkh(xr[p][0], xr[p][1]), rp1 = pkh(xr[p][2], xr[p][3]);
        const unsigned ip0 = pkh(xi[p][0], xi[p][1]), ip1 = pkh(xi[p][2], xi[p][3]);
        const unsigned np0 = ip0 ^ 0x80008000u, np1 = ip1 ^ 0x80008000u;
        FragU Br; Br.u[0] = rp0; Br.u[1] = rp1; Br.u[2] = np0; Br.u[3] = np1;
        FragU Bi; Bi.u[0] = ip0; Bi.u[1] = ip1; Bi.u[2] = rp0; Bi.u[3] = rp1;
        s1r[p] = MFMA(Afrag, Br, zero);
        s1i[p] = MFMA(Afrag, Bi, zero);
    }
    // twiddle tw4096(j*m1), m1 = 4g+reg
#pragma unroll
    for (int p = 0; p < 4; ++p) {
        const int j = (4 * w + p) * 16 + c;
        float sb, cb, ss, cs;
        __sincosf(K1 * (float)(j * 4 * g), &sb, &cb);
        __sincosf(K1 * (float)j, &ss, &cs);
#pragma unroll
        for (int reg = 0; reg < 4; ++reg) {
            const float yr = s1r[p][reg], yi = s1i[p][reg];
            s1r[p][reg] = yr * cb - yi * sb;
            s1i[p][reg] = yr * sb + yi * cb;
            const float nc = cb * cs - sb * ss;
            const float ns = cb * ss + sb * cs;
            cb = nc; sb = ns;
        }
    }
    // LDS1 [m1][o3][o2], o2-block XOR-swizzled: s = (w ^ (c>>2) ^ reg) & 3
#pragma unroll
    for (int reg = 0; reg < 4; ++reg) {
        const int m1 = 4 * g + reg;
        const int half = m1 * 256 + c * 16 + 4 * ((w ^ (c >> 2) ^ reg) & 3);
        uint2 vr, vi;
        vr.x = pkh(s1r[0][reg], s1r[1][reg]); vr.y = pkh(s1r[2][reg], s1r[3][reg]);
        vi.x = pkh(s1i[0][reg], s1i[1][reg]); vi.y = pkh(s1i[2][reg], s1i[3][reg]);
        *(uint2*)(smem + half * 2)        = vr;
        *(uint2*)(smem + 8192 + half * 2) = vi;
    }
    __syncthreads();   // bar1: LDS1 ready (cross-wave)

    // ================= stage 2: A2[m2][o3] = sum_o2 M[m2][o2] T[o2*16+o3] =====
    uint2 rp[4], ip[4];
#pragma unroll
    for (int p = 0; p < 4; ++p) {
        const int m1 = 4 * w + p;
        const int half = m1 * 256 + c * 16 + 4 * ((g ^ (c >> 2) ^ p) & 3);
        rp[p] = *(const uint2*)(smem + half * 2);
        ip[p] = *(const uint2*)(smem + 8192 + half * 2);
    }
    f32x4 s2r[4], s2i[4];
#pragma unroll
    for (int p = 0; p < 4; ++p) {
        FragU Br; Br.u[0] = rp[p].x; Br.u[1] = rp[p].y;
        Br.u[2] = ip[p].x ^ 0x80008000u; Br.u[3] = ip[p].y ^ 0x80008000u;
        FragU Bi; Bi.u[0] = ip[p].x; Bi.u[1] = ip[p].y; Bi.u[2] = rp[p].x; Bi.u[3] = rp[p].y;
        s2r[p] = MFMA(Afrag, Br, zero);
        s2i[p] = MFMA(Afrag, Bi, zero);
    }
    // tw256(o3*m2): o3=c, m2=4g+reg
    {
        float twc[4], tws[4];
        float sb, cb, ss, cs;
        __sincosf(K2 * (float)(c * 4 * g), &sb, &cb);
        __sincosf(K2 * (float)c, &ss, &cs);
#pragma unroll
        for (int reg = 0; reg < 4; ++reg) {
            twc[reg] = cb; tws[reg] = sb;
            const float nc = cb * cs - sb * ss;
            const float ns = cb * ss + sb * cs;
            cb = nc; sb = ns;
        }
#pragma unroll
        for (int p = 0; p < 4; ++p) {
#pragma unroll
            for (int reg = 0; reg < 4; ++reg) {
                const float yr = s2r[p][reg], yi = s2i[p][reg];
                s2r[p][reg] = yr * twc[reg] - yi * tws[reg];
                s2i[p][reg] = yr * tws[reg] + yi * twc[reg];
            }
        }
    }
    // LDS2 [m2][m1][o3] @16384/@24576.
    // slot swizzle: phys_slot = (o3>>2) ^ (m1&3) ^ (m1>>2).
    // writer: m2=4g+reg, m1=4w+p, o3=c  -> slot = (c>>2) ^ p ^ w
#pragma unroll
    for (int reg = 0; reg < 4; ++reg) {
        const int m2 = 4 * g + reg;
#pragma unroll
        for (int p = 0; p < 4; ++p) {
            const int half = m2 * 256 + (4 * w + p) * 16
                           + 4 * (((c >> 2) ^ p ^ w) & 3) + (c & 3);
            *(unsigned short*)(smem + 16384 + half * 2) = h16(s2r[p][reg]);
            *(unsigned short*)(smem + 24576 + half * 2) = h16(s2i[p][reg]);
        }
    }
    __syncthreads();   // bar2: LDS2 ready (cross-wave: reader needs all m1)

    // ================= stage 3: out[n3,m2,m1] = sum_o3 M[n3,o3] U[m2,m1,o3] ===
    // Per m2-tile (m2 = 4w+p): A = M (rows n3), B = U[o3][m1] (cols m1=c,
    // k = o3 = 4g+jj -> b64 at slot g ^ (c&3) ^ (c>>2), conflict-free).
    // D[n3=4g+reg][m1=c] -> lane-contiguous float2 stores (4x128B segments).
    float* __restrict__ og = out;
    const int rslot = 4 * ((g ^ (c & 3) ^ (c >> 2)) & 3);
#pragma unroll
    for (int p = 0; p < 4; ++p) {
        const int m2 = 4 * w + p;
        const int half = m2 * 256 + c * 16 + rslot;
        const uint2 hr = *(const uint2*)(smem + 16384 + half * 2);
        const uint2 hi = *(const uint2*)(smem + 24576 + half * 2);
        FragU Br; Br.u[0] = hr.x; Br.u[1] = hr.y;
        Br.u[2] = hi.x ^ 0x80008000u; Br.u[3] = hi.y ^ 0x80008000u;
        FragU Bi; Bi.u[0] = hi.x; Bi.u[1] = hi.y; Bi.u[2] = hr.x; Bi.u[3] = hr.y;
        const f32x4 vr = MFMA(Afrag, Br, zero);
        const f32x4 vi = MFMA(Afrag, Bi, zero);
#pragma unroll
        for (int reg = 0; reg < 4; ++reg) {
            const size_t k = base + (size_t)((4 * g + reg) * 256 + m2 * 16 + c);
            const f32x2 v = {vr[reg], vi[reg]};
            __builtin_nontemporal_store(v, (f32x2*)(og + 2 * k));
        }
    }
}

extern "C" void kernel_launch(void* const* d_in, const int* in_sizes, int n_in,
                              void* d_out, int out_size, void* d_ws, size_t ws_size,
                              hipStream_t stream)
{
    const float* xre = (const float*)d_in[0];
    const float* xim = (const float*)d_in[1];
    const float* m16 = (const float*)d_in[5];   // (H,16,16,2) fp32
    const int H  = in_sizes[5] / 512;
    const int BH = in_sizes[0] / 4096;
    fft4096_mfma<<<dim3(BH), dim3(256), 0, stream>>>(
        xre, xim, m16, (float*)d_out, H);
}

// Round 13
// 47.025 us; speedup vs baseline: 1.0010x; 1.0010x over previous
//
#include <hip/hip_runtime.h>
#include <stdint.h>

typedef _Float16 f16x8 __attribute__((ext_vector_type(8)));
typedef float    f32x4 __attribute__((ext_vector_type(4)));
typedef float    f32x2 __attribute__((ext_vector_type(2)));

union FragU { unsigned u[4]; f16x8 h; };

__device__ __forceinline__ unsigned pkh(float a, float b) {
    return __builtin_bit_cast(unsigned, __builtin_amdgcn_cvt_pkrtz(a, b));
}

#define MFMA(A, B, C) __builtin_amdgcn_mfma_f32_16x16x32_f16((A).h, (B).h, (C), 0, 0, 0)

#define K1 (-1.5339807878856412e-03f)   /* -2*pi/4096 */
#define K2 (-2.4543692606170259e-02f)   /* -2*pi/256  */

// 4096-pt FFT = 3 radix-16 stages as complex 16x16 GEMMs (K=32 stacking).
// One block per (b,h) row, 4 waves, 2 barriers, direct coalesced stores (r12).
// LDS2 now PACKED half2 (re,im in one u32): writes 32 b16 -> 16 b32,
// stage-3 reads 8 b64 -> 4 b128 + v_perm unpack. DS insts/wave 56 -> 36.
// LDS 32 KiB: LDS1 [m1][o3][o2] fp16 halves @0/@8192;
//             LDS2p [m2][m1][slot^key] half2 @16384 (16 KiB),
//             key = (m1>>1)&3 -> b128 reads <=2-way (free), writes 4-way (16 insts).
__global__ __launch_bounds__(256, 6) void fft4096_mfma(
    const float* __restrict__ xre, const float* __restrict__ xim,
    const float* __restrict__ mat16, float* __restrict__ out, int H)
{
    __shared__ __align__(16) unsigned char smem[32768];

    const int t = threadIdx.x;
    const int w = t >> 6;          // wave 0..3
    const int l = t & 63;
    const int g = l >> 4;          // lane group 0..3
    const int c = l & 15;          // lane col 0..15
    const int bh = blockIdx.x;
    const int h  = bh % H;
    const size_t base = (size_t)bh * 4096;

    // ---- all 64 stage-1 input loads issued first (deep MLP) ----
    float xr[4][4], xi[4][4];
#pragma unroll
    for (int p = 0; p < 4; ++p) {
        const int col = (4 * w + p) * 16 + c;
#pragma unroll
        for (int jj = 0; jj < 4; ++jj) {
            xr[p][jj] = xre[base + (size_t)((4 * g + jj) * 256 + col)];
            xi[p][jj] = xim[base + (size_t)((4 * g + jj) * 256 + col)];
        }
    }

    // ---- M fragment (A = [Mr | Mi], reused by ALL THREE stages) ----
    const float* Mb = mat16 + (size_t)h * 512 + (size_t)c * 32 + g * 8;
    const float4 mf0 = *(const float4*)Mb;
    const float4 mf1 = *(const float4*)(Mb + 4);
    FragU Afrag;
    Afrag.u[0] = pkh(mf0.x, mf0.z); Afrag.u[1] = pkh(mf1.x, mf1.z);
    Afrag.u[2] = pkh(mf0.y, mf0.w); Afrag.u[3] = pkh(mf1.y, mf1.w);

    const f32x4 zero = {0.f, 0.f, 0.f, 0.f};

    // ================= stage 1: Y1[m1][j] = sum_o M[m1][o] x[o*256+j] =========
    f32x4 s1r[4], s1i[4];
#pragma unroll
    for (int p = 0; p < 4; ++p) {
        const unsigned rp0 = pkh(xr[p][0], xr[p][1]), rp1 = pkh(xr[p][2], xr[p][3]);
        const unsigned ip0 = pkh(xi[p][0], xi[p][1]), ip1 = pkh(xi[p][2], xi[p][3]);
        const unsigned np0 = ip0 ^ 0x80008000u, np1 = ip1 ^ 0x80008000u;
        FragU Br; Br.u[0] = rp0; Br.u[1] = rp1; Br.u[2] = np0; Br.u[3] = np1;
        FragU Bi; Bi.u[0] = ip0; Bi.u[1] = ip1; Bi.u[2] = rp0; Bi.u[3] = rp1;
        s1r[p] = MFMA(Afrag, Br, zero);
        s1i[p] = MFMA(Afrag, Bi, zero);
    }
    // twiddle tw4096(j*m1), m1 = 4g+reg
#pragma unroll
    for (int p = 0; p < 4; ++p) {
        const int j = (4 * w + p) * 16 + c;
        float sb, cb, ss, cs;
        __sincosf(K1 * (float)(j * 4 * g), &sb, &cb);
        __sincosf(K1 * (float)j, &ss, &cs);
#pragma unroll
        for (int reg = 0; reg < 4; ++reg) {
            const float yr = s1r[p][reg], yi = s1i[p][reg];
            s1r[p][reg] = yr * cb - yi * sb;
            s1i[p][reg] = yr * sb + yi * cb;
            const float nc = cb * cs - sb * ss;
            const float ns = cb * ss + sb * cs;
            cb = nc; sb = ns;
        }
    }
    // LDS1 [m1][o3][o2], o2-block XOR-swizzled: s = (w ^ (c>>2) ^ reg) & 3
#pragma unroll
    for (int reg = 0; reg < 4; ++reg) {
        const int m1 = 4 * g + reg;
        const int half = m1 * 256 + c * 16 + 4 * ((w ^ (c >> 2) ^ reg) & 3);
        uint2 vr, vi;
        vr.x = pkh(s1r[0][reg], s1r[1][reg]); vr.y = pkh(s1r[2][reg], s1r[3][reg]);
        vi.x = pkh(s1i[0][reg], s1i[1][reg]); vi.y = pkh(s1i[2][reg], s1i[3][reg]);
        *(uint2*)(smem + half * 2)        = vr;
        *(uint2*)(smem + 8192 + half * 2) = vi;
    }
    __syncthreads();   // bar1: LDS1 ready (cross-wave)

    // ================= stage 2: A2[m2][o3] = sum_o2 M[m2][o2] T[o2*16+o3] =====
    uint2 rp[4], ip[4];
#pragma unroll
    for (int p = 0; p < 4; ++p) {
        const int m1 = 4 * w + p;
        const int half = m1 * 256 + c * 16 + 4 * ((g ^ (c >> 2) ^ p) & 3);
        rp[p] = *(const uint2*)(smem + half * 2);
        ip[p] = *(const uint2*)(smem + 8192 + half * 2);
    }
    f32x4 s2r[4], s2i[4];
#pragma unroll
    for (int p = 0; p < 4; ++p) {
        FragU Br; Br.u[0] = rp[p].x; Br.u[1] = rp[p].y;
        Br.u[2] = ip[p].x ^ 0x80008000u; Br.u[3] = ip[p].y ^ 0x80008000u;
        FragU Bi; Bi.u[0] = ip[p].x; Bi.u[1] = ip[p].y; Bi.u[2] = rp[p].x; Bi.u[3] = rp[p].y;
        s2r[p] = MFMA(Afrag, Br, zero);
        s2i[p] = MFMA(Afrag, Bi, zero);
    }
    // tw256(o3*m2): o3=c, m2=4g+reg
    {
        float twc[4], tws[4];
        float sb, cb, ss, cs;
        __sincosf(K2 * (float)(c * 4 * g), &sb, &cb);
        __sincosf(K2 * (float)c, &ss, &cs);
#pragma unroll
        for (int reg = 0; reg < 4; ++reg) {
            twc[reg] = cb; tws[reg] = sb;
            const float nc = cb * cs - sb * ss;
            const float ns = cb * ss + sb * cs;
            cb = nc; sb = ns;
        }
#pragma unroll
        for (int p = 0; p < 4; ++p) {
#pragma unroll
            for (int reg = 0; reg < 4; ++reg) {
                const float yr = s2r[p][reg], yi = s2i[p][reg];
                s2r[p][reg] = yr * twc[reg] - yi * tws[reg];
                s2i[p][reg] = yr * tws[reg] + yi * twc[reg];
            }
        }
    }
    // LDS2p [m2][m1][o3] packed half2 @16384.
    // phys slot = (o3>>2) ^ ((m1>>1)&3); writer: m2=4g+reg, m1=4w+p, o3=c.
    unsigned* l2 = (unsigned*)(smem + 16384);
#pragma unroll
    for (int reg = 0; reg < 4; ++reg) {
        const int m2 = 4 * g + reg;
#pragma unroll
        for (int p = 0; p < 4; ++p) {
            const int m1  = 4 * w + p;
            const int idx = m2 * 256 + m1 * 16
                          + 4 * (((c >> 2) ^ ((m1 >> 1) & 3)) & 3) + (c & 3);
            l2[idx] = pkh(s2r[p][reg], s2i[p][reg]);
        }
    }
    __syncthreads();   // bar2: LDS2 ready (cross-wave: reader needs all m1)

    // ================= stage 3: out[n3,m2,m1] = sum_o3 M[n3,o3] U[m2,m1,o3] ===
    // Per m2-tile: A = M (rows n3), B = U[o3][m1=c]; lane reads one b128
    // (4 packed half2, o3 = 4g..4g+3) at slot g ^ ((c>>1)&3), then v_perm
    // deinterleaves re/im. D[n3=4g+reg][m1=c] -> lane-contiguous f32x2 stores.
    float* __restrict__ og = out;
    const int rkey = (c >> 1) & 3;
#pragma unroll
    for (int p = 0; p < 4; ++p) {
        const int m2  = 4 * w + p;
        const int idx = m2 * 256 + c * 16 + 4 * ((g ^ rkey) & 3);
        const uint4 wv = *(const uint4*)(l2 + idx);
        const unsigned rp0 = __builtin_amdgcn_perm(wv.y, wv.x, 0x05040100u);
        const unsigned rp1 = __builtin_amdgcn_perm(wv.w, wv.z, 0x05040100u);
        const unsigned ip0 = __builtin_amdgcn_perm(wv.y, wv.x, 0x07060302u);
        const unsigned ip1 = __builtin_amdgcn_perm(wv.w, wv.z, 0x07060302u);
        FragU Br; Br.u[0] = rp0; Br.u[1] = rp1;
        Br.u[2] = ip0 ^ 0x80008000u; Br.u[3] = ip1 ^ 0x80008000u;
        FragU Bi; Bi.u[0] = ip0; Bi.u[1] = ip1; Bi.u[2] = rp0; Bi.u[3] = rp1;
        const f32x4 vr = MFMA(Afrag, Br, zero);
        const f32x4 vi = MFMA(Afrag, Bi, zero);
#pragma unroll
        for (int reg = 0; reg < 4; ++reg) {
            const size_t k = base + (size_t)((4 * g + reg) * 256 + m2 * 16 + c);
            const f32x2 v = {vr[reg], vi[reg]};
            __builtin_nontemporal_store(v, (f32x2*)(og + 2 * k));
        }
    }
}

extern "C" void kernel_launch(void* const* d_in, const int* in_sizes, int n_in,
                              void* d_out, int out_size, void* d_ws, size_t ws_size,
                              hipStream_t stream)
{
    const float* xre = (const float*)d_in[0];
    const float* xim = (const float*)d_in[1];
    const float* m16 = (const float*)d_in[5];   // (H,16,16,2) fp32
    const int H  = in_sizes[5] / 512;
    const int BH = in_sizes[0] / 4096;
    fft4096_mfma<<<dim3(BH), dim3(256), 0, stream>>>(
        xre, xim, m16, (float*)d_out, H);
}